// Round 4
// baseline (339.546 us; speedup 1.0000x reference)
//
#include <hip/hip_runtime.h>
#include <hip/hip_bf16.h>

typedef __attribute__((ext_vector_type(8))) short short8;
typedef __attribute__((ext_vector_type(4))) short short4v;
typedef __attribute__((ext_vector_type(4))) float f32x4;
typedef __attribute__((ext_vector_type(16))) float f32x16;
typedef unsigned short u16;

#define ZERO16 (f32x16){0,0,0,0,0,0,0,0,0,0,0,0,0,0,0,0}

__device__ __forceinline__ float b2f(u16 h) {
    unsigned u = ((unsigned)h) << 16;
    float f; __builtin_memcpy(&f, &u, 4); return f;
}
__device__ __forceinline__ u16 f2b(float f) {   // RTNE via HIP intrinsic (compiler lowers to hw cvt)
    __hip_bfloat16 h = __float2bfloat16(f);
    u16 r; __builtin_memcpy(&r, &h, 2); return r;
}
__device__ __forceinline__ void gload16(const void* g, void* l) {
    __builtin_amdgcn_global_load_lds(
        (const __attribute__((address_space(1))) unsigned*)g,
        (__attribute__((address_space(3))) unsigned*)l, 16, 0, 0);
}

// ---------------- problem constants ----------------
#define M_VALID 2640          // B*S*T tokens
#define M_PAD   2688          // 21 * 128
#define K1      3096          // 3072 + 24
#define K1P     3104          // padded to multiple of 32
#define DH      1024
#define CIMG    3072
#define NKV     2688          // padded keys (= M_PAD)
#define NHEAD   16
#define QT      83            // ceil(2640/32) q-tiles
#define NSPLIT  3
#define KSPLIT  896           // keys per split (28 tiles of 32)
#define TILES_PER_SPLIT 28

// ---------------- build fused input (bf16) ----------------
__global__ __launch_bounds__(256) void build_fused_kernel(
    const float* __restrict__ x, const float* __restrict__ cond,
    u16* __restrict__ fused)
{
    int n = blockIdx.x;
    int tid = threadIdx.x;
    const float* xr = x + (size_t)n * CIMG;
    u16* fr = fused + (size_t)n * K1P;
    for (int c = tid * 4; c < CIMG; c += 1024) {
        float4 v = *(const float4*)(xr + c);
        short4v w;
        w[0] = (short)f2b(v.x); w[1] = (short)f2b(v.y);
        w[2] = (short)f2b(v.z); w[3] = (short)f2b(v.w);
        *(short4v*)(fr + c) = w;
    }
    if (tid < 8) {
        int t = n % 3;
        short4v w;
        for (int jj = 0; jj < 4; jj++) {
            int j = tid * 4 + jj;
            float val = 0.f;
            if (j < 24) {
                int f = t * 4 + (j >> 1);          // row in mouse_padded (20 rows, first 8 zero)
                if (f >= 8) val = cond[(f - 8) * 2 + (j & 1)];
            }
            w[jj] = (short)f2b(val);
        }
        *(short4v*)(fr + CIMG + tid * 4) = w;
    }
}

// ---------------- transpose fp32 [K][N] -> bf16 [N][ldt] ----------------
__global__ __launch_bounds__(256) void transpose_bf16_kernel(
    const float* __restrict__ W, u16* __restrict__ Wt, int K, int N, int ldt)
{
    __shared__ float t[32][33];
    int n0 = blockIdx.x * 32, k0 = blockIdx.y * 32;
    int x = threadIdx.x & 31, y0 = threadIdx.x >> 5;   // 32x8
    for (int yy = y0; yy < 32; yy += 8) {
        int k = k0 + yy, n = n0 + x;
        t[yy][x] = (k < K && n < N) ? W[(size_t)k * N + n] : 0.f;
    }
    __syncthreads();
    for (int yy = y0; yy < 32; yy += 8) {
        int n = n0 + yy, k = k0 + x;
        if (n < N && k < ldt) Wt[(size_t)n * ldt + k] = f2b(t[x][yy]);
    }
}

// ---------------- GEMM: C[M][N] = A[M][K] @ Bt[N][K]^T  (bf16 in, f32 acc) ----------------
// EPI 0: +bias, tanh-GELU -> bf16       EPI 1: +bias -> bf16
// EPI 2: +bias + resid -> f32 (rows < Mvalid)
template<int EPI, int BN>
__global__ __launch_bounds__(256) void gemm_kernel(
    const u16* __restrict__ A, const u16* __restrict__ Bt,
    const float* __restrict__ bias, const float* __restrict__ resid,
    u16* __restrict__ Cb, float* __restrict__ Cf,
    int N, int K, int Mvalid)
{
    __shared__ u16 As[128 * 32];
    __shared__ u16 Bs[BN * 32];
    constexpr int NJ = BN / 32;
    const int tid = threadIdx.x;
    const int lane = tid & 63, wid = tid >> 6;
    const int l15 = lane & 15, l4 = lane >> 4;
    const int m0 = blockIdx.y * 128, n0 = blockIdx.x * BN;
    const int wr = (wid >> 1) * 64, wc = (wid & 1) * (BN / 2);

    f32x4 acc[4][NJ];
#pragma unroll
    for (int i = 0; i < 4; i++)
#pragma unroll
        for (int j = 0; j < NJ; j++) acc[i][j] = (f32x4){0.f, 0.f, 0.f, 0.f};

    const int r0 = tid >> 2, sg = (tid & 3) * 8;

    for (int k0 = 0; k0 < K; k0 += 32) {
        __syncthreads();
        gload16(A + (size_t)(m0 + r0) * K + k0 + sg, (char*)As + tid * 16);
        gload16(A + (size_t)(m0 + r0 + 64) * K + k0 + sg, (char*)As + tid * 16 + 4096);
        gload16(Bt + (size_t)(n0 + r0) * K + k0 + sg, (char*)Bs + tid * 16);
        if (BN == 128)
            gload16(Bt + (size_t)(n0 + r0 + 64) * K + k0 + sg, (char*)Bs + tid * 16 + 4096);
        __syncthreads();
        short8 af[4], bfr[NJ];
#pragma unroll
        for (int i = 0; i < 4; i++)
            af[i] = *(const short8*)(&As[(wr + i * 16 + l15) * 32 + l4 * 8]);
#pragma unroll
        for (int j = 0; j < NJ; j++)
            bfr[j] = *(const short8*)(&Bs[(wc + j * 16 + l15) * 32 + l4 * 8]);
#pragma unroll
        for (int i = 0; i < 4; i++)
#pragma unroll
            for (int j = 0; j < NJ; j++)
                acc[i][j] = __builtin_amdgcn_mfma_f32_16x16x32_bf16(af[i], bfr[j], acc[i][j], 0, 0, 0);
    }

#pragma unroll
    for (int i = 0; i < 4; i++) {
#pragma unroll
        for (int j = 0; j < NJ; j++) {
#pragma unroll
            for (int r = 0; r < 4; r++) {
                int row = m0 + wr + i * 16 + l4 * 4 + r;
                int col = n0 + wc + j * 16 + l15;
                float v = acc[i][j][r] + bias[col];
                if (EPI == 0) {
                    float t = v + 0.044715f * v * v * v;
                    float g = 0.5f * v * (1.0f + tanhf(0.7978845608028654f * t));
                    Cb[(size_t)row * N + col] = f2b(g);
                } else if (EPI == 1) {
                    Cb[(size_t)row * N + col] = f2b(v);
                } else {
                    if (row < Mvalid)
                        Cf[(size_t)row * N + col] = v + resid[(size_t)row * N + col];
                }
            }
        }
    }
}

// ---------------- LayerNorm over 1024 (bf16 -> bf16) ----------------
__global__ __launch_bounds__(256) void ln_kernel(
    const u16* __restrict__ h2, const float* __restrict__ g,
    const float* __restrict__ b, u16* __restrict__ out)
{
    int row = blockIdx.x;
    int tid = threadIdx.x;
    const u16* p = h2 + (size_t)row * DH;
    float v[4];
#pragma unroll
    for (int i = 0; i < 4; i++) v[i] = b2f(p[tid * 4 + i]);
    float s1 = v[0] + v[1] + v[2] + v[3];
    float s2 = v[0]*v[0] + v[1]*v[1] + v[2]*v[2] + v[3]*v[3];
    for (int m = 1; m < 64; m <<= 1) { s1 += __shfl_xor(s1, m); s2 += __shfl_xor(s2, m); }
    __shared__ float a1[4], a2[4];
    int w = tid >> 6;
    if ((tid & 63) == 0) { a1[w] = s1; a2[w] = s2; }
    __syncthreads();
    s1 = a1[0] + a1[1] + a1[2] + a1[3];
    s2 = a2[0] + a2[1] + a2[2] + a2[3];
    float mean = s1 * (1.0f / 1024.0f);
    float var = s2 * (1.0f / 1024.0f) - mean * mean;
    float rs = rsqrtf(var + 1e-5f);
    u16* q = out + (size_t)row * DH;
#pragma unroll
    for (int i = 0; i < 4; i++) {
        int c = tid * 4 + i;
        q[c] = f2b((v[i] - mean) * rs * g[c] + b[c]);
    }
}

// ---------------- RMSNorm q,k + split + V transpose (Q pre-scaled by 1/8) ----------------
__global__ __launch_bounds__(256) void rmsnorm_kernel(
    const u16* __restrict__ qkv, const float* __restrict__ qw, const float* __restrict__ kw,
    u16* __restrict__ qb, u16* __restrict__ kb, u16* __restrict__ vt)
{
    int n = blockIdx.x;
    int lane = threadIdx.x & 63, w = threadIdx.x >> 6;
#pragma unroll
    for (int hh = 0; hh < 4; hh++) {
        int h = w * 4 + hh;
        float qv = b2f(qkv[(size_t)n * 3072 + h * 64 + lane]);
        float kv = b2f(qkv[(size_t)n * 3072 + 1024 + h * 64 + lane]);
        float vv = b2f(qkv[(size_t)n * 3072 + 2048 + h * 64 + lane]);
        float sq = qv * qv, sk = kv * kv;
        for (int m = 1; m < 64; m <<= 1) { sq += __shfl_xor(sq, m); sk += __shfl_xor(sk, m); }
        float rq = rsqrtf(sq * (1.0f / 64.0f) + 1e-6f);
        float rk = rsqrtf(sk * (1.0f / 64.0f) + 1e-6f);
        qb[(size_t)n * DH + h * 64 + lane] = f2b(qv * rq * qw[lane] * 0.125f);  // fold 1/sqrt(64)
        kb[(size_t)n * DH + h * 64 + lane] = f2b(kv * rk * kw[lane]);
        vt[(size_t)(h * 64 + lane) * NKV + n] = f2b(vv);
    }
}

// ---------------- attention tile: softmax + PV ----------------
__device__ __forceinline__ void attn_tile(
    f32x16& st, float& mr, float& lr, f32x16& o0, f32x16& o1,
    u16* Pbuf, const short8* vv, int kq, int hi)
{
    float tmax = st[0];
#pragma unroll
    for (int r = 1; r < 16; r++) tmax = fmaxf(tmax, st[r]);
    tmax = fmaxf(tmax, __shfl_xor(tmax, 32));
    if (__any(tmax - mr > 8.0f)) {       // defer-max (T13)
        float mn = fmaxf(mr, tmax);
        float corr = __expf(mr - mn);
        mr = mn; lr *= corr;
#pragma unroll
        for (int r = 0; r < 16; r++) {   // per-O-row factor: O rows are query rl, not kq
            float cr = __shfl(corr, (r & 3) + 8 * (r >> 2) + 4 * hi);
            o0[r] *= cr; o1[r] *= cr;
        }
    }
    float sum = 0.f;
    float p[16];
#pragma unroll
    for (int r = 0; r < 16; r++) { p[r] = __expf(st[r] - mr); sum += p[r]; }
    lr += sum + __shfl_xor(sum, 32);
#pragma unroll
    for (int g = 0; g < 4; g++) {
        short4v w;
#pragma unroll
        for (int e = 0; e < 4; e++) w[e] = (short)f2b(p[g * 4 + e]);
        *(short4v*)((char*)Pbuf + kq * 80 + g * 16 + hi * 8) = w;
    }
    short8 pa0 = *(const short8*)((const char*)Pbuf + kq * 80 + hi * 16);
    short8 pa1 = *(const short8*)((const char*)Pbuf + kq * 80 + 32 + hi * 16);
    o0 = __builtin_amdgcn_mfma_f32_32x32x16_bf16(pa0, vv[0], o0, 0, 0, 0);
    o0 = __builtin_amdgcn_mfma_f32_32x32x16_bf16(pa1, vv[1], o0, 0, 0, 0);
    o1 = __builtin_amdgcn_mfma_f32_32x32x16_bf16(pa0, vv[2], o1, 0, 0, 0);
    o1 = __builtin_amdgcn_mfma_f32_32x32x16_bf16(pa1, vv[3], o1, 0, 0, 0);
}

// ---------------- flash attention, KV-split: block = (split, head, q-tile) ----------------
// Writes unnormalized fp32 partials O_s plus (m_s, l_s) per (query, head, split).
__global__ __launch_bounds__(64) void attn_kernel(
    const u16* __restrict__ Q, const u16* __restrict__ Kb,
    const u16* __restrict__ Vt, float* __restrict__ part, float* __restrict__ ml)
{
    __shared__ u16 P[32 * 40];
    const int bid = blockIdx.x;
    const int s   = bid / (NHEAD * QT);
    const int rem = bid % (NHEAD * QT);
    const int h   = rem / QT;
    const int qt  = rem % QT;
    const int lane = threadIdx.x;
    const int kq = lane & 31;
    const int hi = lane >> 5;
    const int q0 = qt * 32;
    const int kbase = s * KSPLIT;
    const u16* Kh = Kb + h * 64;
    const u16* V0 = Vt + (size_t)(h * 64 + kq) * NKV;
    const u16* V1 = Vt + (size_t)(h * 64 + 32 + kq) * NKV;

    short8 qf[4];
#pragma unroll
    for (int d = 0; d < 4; d++)
        qf[d] = *(const short8*)(Q + (size_t)(q0 + kq) * DH + h * 64 + d * 16 + hi * 8);

    f32x16 o0 = ZERO16, o1 = ZERO16;
    float mr = -3.0e38f, lr = 0.f;

    short8 kf[4];
#pragma unroll
    for (int d = 0; d < 4; d++)
        kf[d] = *(const short8*)(Kh + (size_t)(kbase + kq) * DH + d * 16 + hi * 8);

    for (int i = 0; i < TILES_PER_SPLIT; i++) {
        const int k0 = kbase + i * 32;
        short8 vv[4];
        vv[0] = *(const short8*)(V0 + k0 + hi * 8);
        vv[1] = *(const short8*)(V0 + k0 + 16 + hi * 8);
        vv[2] = *(const short8*)(V1 + k0 + hi * 8);
        vv[3] = *(const short8*)(V1 + k0 + 16 + hi * 8);

        f32x16 st = ZERO16;
#pragma unroll
        for (int d = 0; d < 4; d++)
            st = __builtin_amdgcn_mfma_f32_32x32x16_bf16(kf[d], qf[d], st, 0, 0, 0);

        if (i < TILES_PER_SPLIT - 1) {   // prefetch next K tile
#pragma unroll
            for (int d = 0; d < 4; d++)
                kf[d] = *(const short8*)(Kh + (size_t)(k0 + 32 + kq) * DH + d * 16 + hi * 8);
        }

        if (k0 + 32 > M_VALID) {         // mask pad keys (only trailing tiles of last split)
#pragma unroll
            for (int r = 0; r < 16; r++) {
                int key = k0 + (r & 3) + 8 * (r >> 2) + 4 * hi;
                if (key >= M_VALID) st[r] = -3.0e38f;
            }
        }
        attn_tile(st, mr, lr, o0, o1, P, vv, kq, hi);
    }

    // ---- write fp32 partials ----
#pragma unroll
    for (int r = 0; r < 16; r++) {
        int rl = (r & 3) + 8 * (r >> 2) + 4 * hi;
        int qrow = q0 + rl;
        if (qrow < M_VALID) {
            float* pp = part + ((size_t)s * M_PAD + qrow) * DH + h * 64;
            pp[kq] = o0[r];
            pp[kq + 32] = o1[r];
        }
    }
    if (hi == 0 && q0 + kq < M_VALID) {
        float* mlp = ml + (((size_t)s * NHEAD + h) * M_PAD + q0 + kq) * 2;
        mlp[0] = mr; mlp[1] = lr;
    }
}

// ---------------- merge KV-split partials -> bf16 obf (permuted rows) ----------------
__global__ __launch_bounds__(256) void attn_merge_kernel(
    const float* __restrict__ part, const float* __restrict__ ml, u16* __restrict__ obf)
{
    const int q = blockIdx.x;           // 0..M_VALID-1
    const int t = threadIdx.x;
    const int h = t >> 4, i = t & 15;   // head, 4-dim group
    float m[NSPLIT], l[NSPLIT];
#pragma unroll
    for (int s = 0; s < NSPLIT; s++) {
        const float* mlp = ml + (((size_t)s * NHEAD + h) * M_PAD + q) * 2;
        m[s] = mlp[0]; l[s] = mlp[1];
    }
    float M = fmaxf(fmaxf(m[0], m[1]), m[2]);
    float c[NSPLIT], L = 0.f;
#pragma unroll
    for (int s = 0; s < NSPLIT; s++) { c[s] = __expf(m[s] - M); L += c[s] * l[s]; }
    float inv = 1.0f / L;
    float4 acc = {0.f, 0.f, 0.f, 0.f};
#pragma unroll
    for (int s = 0; s < NSPLIT; s++) {
        float4 v = *(const float4*)(part + ((size_t)s * M_PAD + q) * DH + h * 64 + i * 4);
        acc.x += c[s] * v.x; acc.y += c[s] * v.y; acc.z += c[s] * v.z; acc.w += c[s] * v.w;
    }
    int mrow = (q % 3) * 880 + q / 3;   // (S,T) -> (T,S) permute
    short4v w;
    w[0] = (short)f2b(acc.x * inv); w[1] = (short)f2b(acc.y * inv);
    w[2] = (short)f2b(acc.z * inv); w[3] = (short)f2b(acc.w * inv);
    *(short4v*)(obf + (size_t)mrow * DH + h * 64 + i * 4) = w;
}

// ---------------- launch ----------------
extern "C" void kernel_launch(void* const* d_in, const int* in_sizes, int n_in,
                              void* d_out, int out_size, void* d_ws, size_t ws_size,
                              hipStream_t stream)
{
    const float* x      = (const float*)d_in[0];
    const float* cond   = (const float*)d_in[1];
    const float* w1     = (const float*)d_in[2];
    const float* b1     = (const float*)d_in[3];
    const float* w2     = (const float*)d_in[4];
    const float* b2     = (const float*)d_in[5];
    const float* ln_g   = (const float*)d_in[6];
    const float* ln_b   = (const float*)d_in[7];
    const float* wqkv   = (const float*)d_in[8];
    const float* bqkv   = (const float*)d_in[9];
    const float* qn_w   = (const float*)d_in[10];
    const float* kn_w   = (const float*)d_in[11];
    const float* wproj  = (const float*)d_in[12];
    const float* bproj  = (const float*)d_in[13];
    float* out = (float*)d_out;

    char* ws = (char*)d_ws;
    size_t off = 0;
    auto alloc = [&](size_t bytes) { size_t o = off; off += (bytes + 255) & ~(size_t)255; return o; };

    size_t off_fused  = alloc((size_t)M_PAD * K1P * 2);
    size_t off_w1t    = alloc((size_t)DH * K1P * 2);
    size_t off_w2t    = alloc((size_t)DH * DH * 2);
    size_t off_wqkvt  = alloc((size_t)3072 * DH * 2);
    size_t off_wprojt = alloc((size_t)CIMG * DH * 2);
    size_t off_h1     = alloc((size_t)M_PAD * DH * 2);   // ┐ reused by attn as fp32
    size_t off_h2     = alloc((size_t)M_PAD * DH * 2);   // │ partial buffer:
    size_t off_h2ln   = alloc((size_t)M_PAD * DH * 2);   // │ 3 * M_PAD*DH*4 bytes
    size_t off_qkv    = alloc((size_t)M_PAD * 3072 * 2); // ┘ = exactly these 4 regions
    size_t off_qbf    = alloc((size_t)M_PAD * DH * 2);
    size_t off_kbf    = alloc((size_t)M_PAD * DH * 2);
    size_t off_vt     = alloc((size_t)DH * NKV * 2);
    size_t off_obf    = alloc((size_t)M_PAD * DH * 2);
    (void)ws_size;

    u16* fused  = (u16*)(ws + off_fused);
    u16* w1t    = (u16*)(ws + off_w1t);
    u16* w2t    = (u16*)(ws + off_w2t);
    u16* wqkvt  = (u16*)(ws + off_wqkvt);
    u16* wprojt = (u16*)(ws + off_wprojt);
    u16* h1     = (u16*)(ws + off_h1);
    u16* h2     = (u16*)(ws + off_h2);
    u16* h2ln   = (u16*)(ws + off_h2ln);
    u16* qkvb   = (u16*)(ws + off_qkv);
    u16* qbf    = (u16*)(ws + off_qbf);
    u16* kbf    = (u16*)(ws + off_kbf);
    u16* vt     = (u16*)(ws + off_vt);
    u16* obf    = (u16*)(ws + off_obf);
    float* part = (float*)(ws + off_h1);     // 3*M_PAD*DH fp32 over dead h1..qkv
    float* mlbf = (float*)(ws + off_fused);  // 3*16*M_PAD*2 fp32 over dead fused

    // zero pad regions (pad K rows must be finite-and-masked; fused pads feed gemm1)
    hipMemsetAsync(ws + off_fused + (size_t)M_VALID * K1P * 2, 0, (size_t)(M_PAD - M_VALID) * K1P * 2, stream);
    hipMemsetAsync(ws + off_kbf + (size_t)M_VALID * DH * 2, 0, (size_t)(M_PAD - M_VALID) * DH * 2, stream);

    build_fused_kernel<<<M_VALID, 256, 0, stream>>>(x, cond, fused);
    transpose_bf16_kernel<<<dim3(DH / 32, K1P / 32), 256, 0, stream>>>(w1, w1t, K1, DH, K1P);
    transpose_bf16_kernel<<<dim3(DH / 32, DH / 32), 256, 0, stream>>>(w2, w2t, DH, DH, DH);
    transpose_bf16_kernel<<<dim3(3072 / 32, DH / 32), 256, 0, stream>>>(wqkv, wqkvt, DH, 3072, DH);
    transpose_bf16_kernel<<<dim3(CIMG / 32, DH / 32), 256, 0, stream>>>(wproj, wprojt, DH, CIMG, DH);

    gemm_kernel<0, 64><<<dim3(DH / 64, M_PAD / 128), 256, 0, stream>>>(fused, w1t, b1, nullptr, h1, nullptr, DH, K1P, M_PAD);
    gemm_kernel<1, 64><<<dim3(DH / 64, M_PAD / 128), 256, 0, stream>>>(h1, w2t, b2, nullptr, h2, nullptr, DH, DH, M_PAD);
    ln_kernel<<<M_PAD, 256, 0, stream>>>(h2, ln_g, ln_b, h2ln);
    gemm_kernel<1, 128><<<dim3(3072 / 128, M_PAD / 128), 256, 0, stream>>>(h2ln, wqkvt, bqkv, nullptr, qkvb, nullptr, 3072, DH, M_PAD);
    rmsnorm_kernel<<<M_VALID, 256, 0, stream>>>(qkvb, qn_w, kn_w, qbf, kbf, vt);
    attn_kernel<<<dim3(NSPLIT * NHEAD * QT), 64, 0, stream>>>(qbf, kbf, vt, part, mlbf);
    attn_merge_kernel<<<M_VALID, 256, 0, stream>>>(part, mlbf, obf);
    gemm_kernel<2, 128><<<dim3(CIMG / 128, M_PAD / 128), 256, 0, stream>>>(obf, wprojt, bproj, x, nullptr, out, CIMG, DH, M_VALID);
}

// Round 5
// 267.225 us; speedup vs baseline: 1.2706x; 1.2706x over previous
//
#include <hip/hip_runtime.h>
#include <hip/hip_bf16.h>

typedef __attribute__((ext_vector_type(8))) short short8;
typedef __attribute__((ext_vector_type(4))) short short4v;
typedef __attribute__((ext_vector_type(4))) float f32x4;
typedef __attribute__((ext_vector_type(16))) float f32x16;
typedef unsigned short u16;

#define ZERO16 (f32x16){0,0,0,0,0,0,0,0,0,0,0,0,0,0,0,0}

__device__ __forceinline__ float b2f(u16 h) {
    unsigned u = ((unsigned)h) << 16;
    float f; __builtin_memcpy(&f, &u, 4); return f;
}
__device__ __forceinline__ u16 f2b(float f) {   // RTNE via HIP intrinsic
    __hip_bfloat16 h = __float2bfloat16(f);
    u16 r; __builtin_memcpy(&r, &h, 2); return r;
}
__device__ __forceinline__ void gload16(const void* g, void* l) {
    __builtin_amdgcn_global_load_lds(
        (const __attribute__((address_space(1))) unsigned*)g,
        (__attribute__((address_space(3))) unsigned*)l, 16, 0, 0);
}

// ---------------- problem constants ----------------
#define M_VALID 2640          // B*S*T tokens
#define M_PAD   2688          // 21 * 128
#define K1      3096          // 3072 + 24
#define K1P     3104          // padded to multiple of 32
#define DH      1024
#define CIMG    3072
#define NHEAD   16
#define NT      84            // 32-token tiles (2688 tokens)
#define QT      83            // q-tiles used (covers 2640)
#define NSPLIT  3
#define TILES_PER_SPLIT 28    // 3*28 = 84 tiles

// ---------------- build fused input (bf16) ----------------
__global__ __launch_bounds__(256) void build_fused_kernel(
    const float* __restrict__ x, const float* __restrict__ cond,
    u16* __restrict__ fused)
{
    int n = blockIdx.x;
    int tid = threadIdx.x;
    const float* xr = x + (size_t)n * CIMG;
    u16* fr = fused + (size_t)n * K1P;
    for (int c = tid * 4; c < CIMG; c += 1024) {
        float4 v = *(const float4*)(xr + c);
        short4v w;
        w[0] = (short)f2b(v.x); w[1] = (short)f2b(v.y);
        w[2] = (short)f2b(v.z); w[3] = (short)f2b(v.w);
        *(short4v*)(fr + c) = w;
    }
    if (tid < 8) {
        int t = n % 3;
        short4v w;
        for (int jj = 0; jj < 4; jj++) {
            int j = tid * 4 + jj;
            float val = 0.f;
            if (j < 24) {
                int f = t * 4 + (j >> 1);          // row in mouse_padded (20 rows, first 8 zero)
                if (f >= 8) val = cond[(f - 8) * 2 + (j & 1)];
            }
            w[jj] = (short)f2b(val);
        }
        *(short4v*)(fr + CIMG + tid * 4) = w;
    }
}

// ---------------- transpose fp32 [K][N] -> bf16 [N][ldt] ----------------
__global__ __launch_bounds__(256) void transpose_bf16_kernel(
    const float* __restrict__ W, u16* __restrict__ Wt, int K, int N, int ldt)
{
    __shared__ float t[32][33];
    int n0 = blockIdx.x * 32, k0 = blockIdx.y * 32;
    int x = threadIdx.x & 31, y0 = threadIdx.x >> 5;   // 32x8
    for (int yy = y0; yy < 32; yy += 8) {
        int k = k0 + yy, n = n0 + x;
        t[yy][x] = (k < K && n < N) ? W[(size_t)k * N + n] : 0.f;
    }
    __syncthreads();
    for (int yy = y0; yy < 32; yy += 8) {
        int n = n0 + yy, k = k0 + x;
        if (n < N && k < ldt) Wt[(size_t)n * ldt + k] = f2b(t[x][yy]);
    }
}

// ---------------- GEMM: C[M][N] = A[M][K] @ Bt[N][K]^T  (bf16 in, f32 acc) ----------------
template<int EPI, int BN>
__global__ __launch_bounds__(256) void gemm_kernel(
    const u16* __restrict__ A, const u16* __restrict__ Bt,
    const float* __restrict__ bias, const float* __restrict__ resid,
    u16* __restrict__ Cb, float* __restrict__ Cf,
    int N, int K, int Mvalid)
{
    __shared__ u16 As[128 * 32];
    __shared__ u16 Bs[BN * 32];
    constexpr int NJ = BN / 32;
    const int tid = threadIdx.x;
    const int lane = tid & 63, wid = tid >> 6;
    const int l15 = lane & 15, l4 = lane >> 4;
    const int m0 = blockIdx.y * 128, n0 = blockIdx.x * BN;
    const int wr = (wid >> 1) * 64, wc = (wid & 1) * (BN / 2);

    f32x4 acc[4][NJ];
#pragma unroll
    for (int i = 0; i < 4; i++)
#pragma unroll
        for (int j = 0; j < NJ; j++) acc[i][j] = (f32x4){0.f, 0.f, 0.f, 0.f};

    const int r0 = tid >> 2, sg = (tid & 3) * 8;

    for (int k0 = 0; k0 < K; k0 += 32) {
        __syncthreads();
        gload16(A + (size_t)(m0 + r0) * K + k0 + sg, (char*)As + tid * 16);
        gload16(A + (size_t)(m0 + r0 + 64) * K + k0 + sg, (char*)As + tid * 16 + 4096);
        gload16(Bt + (size_t)(n0 + r0) * K + k0 + sg, (char*)Bs + tid * 16);
        if (BN == 128)
            gload16(Bt + (size_t)(n0 + r0 + 64) * K + k0 + sg, (char*)Bs + tid * 16 + 4096);
        __syncthreads();
        short8 af[4], bfr[NJ];
#pragma unroll
        for (int i = 0; i < 4; i++)
            af[i] = *(const short8*)(&As[(wr + i * 16 + l15) * 32 + l4 * 8]);
#pragma unroll
        for (int j = 0; j < NJ; j++)
            bfr[j] = *(const short8*)(&Bs[(wc + j * 16 + l15) * 32 + l4 * 8]);
#pragma unroll
        for (int i = 0; i < 4; i++)
#pragma unroll
            for (int j = 0; j < NJ; j++)
                acc[i][j] = __builtin_amdgcn_mfma_f32_16x16x32_bf16(af[i], bfr[j], acc[i][j], 0, 0, 0);
    }

#pragma unroll
    for (int i = 0; i < 4; i++) {
#pragma unroll
        for (int j = 0; j < NJ; j++) {
#pragma unroll
            for (int r = 0; r < 4; r++) {
                int row = m0 + wr + i * 16 + l4 * 4 + r;
                int col = n0 + wc + j * 16 + l15;
                float v = acc[i][j][r] + bias[col];
                if (EPI == 0) {
                    float t = v + 0.044715f * v * v * v;
                    float g = 0.5f * v * (1.0f + tanhf(0.7978845608028654f * t));
                    Cb[(size_t)row * N + col] = f2b(g);
                } else if (EPI == 1) {
                    Cb[(size_t)row * N + col] = f2b(v);
                } else {
                    if (row < Mvalid)
                        Cf[(size_t)row * N + col] = v + resid[(size_t)row * N + col];
                }
            }
        }
    }
}

// ---------------- LayerNorm over 1024 (bf16 -> bf16) ----------------
__global__ __launch_bounds__(256) void ln_kernel(
    const u16* __restrict__ h2, const float* __restrict__ g,
    const float* __restrict__ b, u16* __restrict__ out)
{
    int row = blockIdx.x;
    int tid = threadIdx.x;
    const u16* p = h2 + (size_t)row * DH;
    float v[4];
#pragma unroll
    for (int i = 0; i < 4; i++) v[i] = b2f(p[tid * 4 + i]);
    float s1 = v[0] + v[1] + v[2] + v[3];
    float s2 = v[0]*v[0] + v[1]*v[1] + v[2]*v[2] + v[3]*v[3];
    for (int m = 1; m < 64; m <<= 1) { s1 += __shfl_xor(s1, m); s2 += __shfl_xor(s2, m); }
    __shared__ float a1[4], a2[4];
    int w = tid >> 6;
    if ((tid & 63) == 0) { a1[w] = s1; a2[w] = s2; }
    __syncthreads();
    s1 = a1[0] + a1[1] + a1[2] + a1[3];
    s2 = a2[0] + a2[1] + a2[2] + a2[3];
    float mean = s1 * (1.0f / 1024.0f);
    float var = s2 * (1.0f / 1024.0f) - mean * mean;
    float rs = rsqrtf(var + 1e-5f);
    u16* q = out + (size_t)row * DH;
#pragma unroll
    for (int i = 0; i < 4; i++) {
        int c = tid * 4 + i;
        q[c] = f2b((v[i] - mean) * rs * g[c] + b[c]);
    }
}

// ---------------- fragmentize: RMSNorm(q,k) + MFMA-fragment layout for Q,K,V ----------------
// Chunk (h, tile, d, kq, hi) at ((h*NT+tile)*4+d)*512 + kq*16 + hi*8 holds:
//   Q/K[token=tile*32+kq][h*64 + d*16 + hi*8 .. +8]
// V chunk (h, tile, fd=half*2+ks, kq, hi) holds:
//   V[key=tile*32+(fd&1)*16+hi*8+e][h*64 + (fd>>1)*32 + kq]   (transposed)
__global__ __launch_bounds__(256) void fragmentize_kernel(
    const u16* __restrict__ qkv, const float* __restrict__ qw, const float* __restrict__ kw,
    u16* __restrict__ Qf, u16* __restrict__ Kf, u16* __restrict__ Vf)
{
    __shared__ u16 Vlds[8 * 32 * 80];    // [hh][token][dim], row stride 80 (160B, conflict-relief)
    const int kt = blockIdx.x;           // 0..NT-1
    const int hg = blockIdx.y;           // 0..1 (8 heads each)
    const int tid = threadIdx.x;
    const int t32 = tid >> 3, c8 = tid & 7;
    const int n = kt * 32 + t32;
    const u16* row = qkv + (size_t)n * 3072;

    // stage V into LDS
#pragma unroll
    for (int hh = 0; hh < 8; hh++) {
        short8 v = *(const short8*)(row + 2048 + (hg * 8 + hh) * 64 + c8 * 8);
        *(short8*)(&Vlds[(hh * 32 + t32) * 80 + c8 * 8]) = v;
    }

    // q/k sum of squares per head (8 threads per token, xor-reduce over c8)
    float sq[8], sk[8];
#pragma unroll
    for (int hh = 0; hh < 8; hh++) {
        int h = hg * 8 + hh;
        short8 qv = *(const short8*)(row + h * 64 + c8 * 8);
        short8 kv = *(const short8*)(row + 1024 + h * 64 + c8 * 8);
        float aq = 0.f, ak = 0.f;
#pragma unroll
        for (int e = 0; e < 8; e++) {
            float fq = b2f((u16)qv[e]); aq += fq * fq;
            float fk = b2f((u16)kv[e]); ak += fk * fk;
        }
        sq[hh] = aq; sk[hh] = ak;
    }
#pragma unroll
    for (int m = 1; m < 8; m <<= 1) {
#pragma unroll
        for (int hh = 0; hh < 8; hh++) {
            sq[hh] += __shfl_xor(sq[hh], m);
            sk[hh] += __shfl_xor(sk[hh], m);
        }
    }

    float qwv[8], kwv[8];
#pragma unroll
    for (int e = 0; e < 8; e++) { qwv[e] = qw[c8 * 8 + e]; kwv[e] = kw[c8 * 8 + e]; }

    // normalize + write Q/K fragments (fold 1/sqrt(64) into q)
#pragma unroll
    for (int hh = 0; hh < 8; hh++) {
        int h = hg * 8 + hh;
        float rq = rsqrtf(sq[hh] * (1.0f / 64.0f) + 1e-6f) * 0.125f;
        float rk = rsqrtf(sk[hh] * (1.0f / 64.0f) + 1e-6f);
        short8 qv = *(const short8*)(row + h * 64 + c8 * 8);
        short8 kv = *(const short8*)(row + 1024 + h * 64 + c8 * 8);
        short8 qo, ko;
#pragma unroll
        for (int e = 0; e < 8; e++) {
            qo[e] = (short)f2b(b2f((u16)qv[e]) * rq * qwv[e]);
            ko[e] = (short)f2b(b2f((u16)kv[e]) * rk * kwv[e]);
        }
        size_t base = (((size_t)(h * NT + kt) * 4 + (c8 >> 1)) << 9) + t32 * 16 + (c8 & 1) * 8;
        *(short8*)(Qf + base) = qo;
        *(short8*)(Kf + base) = ko;
    }

    __syncthreads();

    // transposed V fragments
    const int fd = tid >> 6;             // 0..3
    const int lkq = (tid & 63) >> 1, lhi = tid & 1;
#pragma unroll
    for (int hh = 0; hh < 8; hh++) {
        int h = hg * 8 + hh;
        short8 o;
#pragma unroll
        for (int e = 0; e < 8; e++)
            o[e] = (short)Vlds[(hh * 32 + (fd & 1) * 16 + lhi * 8 + e) * 80 + (fd >> 1) * 32 + lkq];
        *(short8*)(Vf + (((size_t)(h * NT + kt) * 4 + fd) << 9) + lkq * 16 + lhi * 8) = o;
    }
}

// ---------------- attention tile: softmax + PV ----------------
__device__ __forceinline__ void attn_tile(
    f32x16& st, float& mr, float& lr, f32x16& o0, f32x16& o1,
    u16* Pbuf, const short8* vv, int kq, int hi)
{
    float tmax = st[0];
#pragma unroll
    for (int r = 1; r < 16; r++) tmax = fmaxf(tmax, st[r]);
    tmax = fmaxf(tmax, __shfl_xor(tmax, 32));
    if (__any(tmax - mr > 8.0f)) {       // defer-max (T13)
        float mn = fmaxf(mr, tmax);
        float corr = __expf(mr - mn);
        mr = mn; lr *= corr;
#pragma unroll
        for (int r = 0; r < 16; r++) {   // per-O-row factor: O rows are query rl, not kq
            float cr = __shfl(corr, (r & 3) + 8 * (r >> 2) + 4 * hi);
            o0[r] *= cr; o1[r] *= cr;
        }
    }
    float sum = 0.f;
    float p[16];
#pragma unroll
    for (int r = 0; r < 16; r++) { p[r] = __expf(st[r] - mr); sum += p[r]; }
    lr += sum + __shfl_xor(sum, 32);
#pragma unroll
    for (int g = 0; g < 4; g++) {
        short4v w;
#pragma unroll
        for (int e = 0; e < 4; e++) w[e] = (short)f2b(p[g * 4 + e]);
        *(short4v*)((char*)Pbuf + kq * 80 + g * 16 + hi * 8) = w;
    }
    short8 pa0 = *(const short8*)((const char*)Pbuf + kq * 80 + hi * 16);
    short8 pa1 = *(const short8*)((const char*)Pbuf + kq * 80 + 32 + hi * 16);
    o0 = __builtin_amdgcn_mfma_f32_32x32x16_bf16(pa0, vv[0], o0, 0, 0, 0);
    o0 = __builtin_amdgcn_mfma_f32_32x32x16_bf16(pa1, vv[1], o0, 0, 0, 0);
    o1 = __builtin_amdgcn_mfma_f32_32x32x16_bf16(pa0, vv[2], o1, 0, 0, 0);
    o1 = __builtin_amdgcn_mfma_f32_32x32x16_bf16(pa1, vv[3], o1, 0, 0, 0);
}

// ---------------- flash attention, KV-split, fragment inputs ----------------
__global__ __launch_bounds__(64, 4) void attn_kernel(
    const u16* __restrict__ Qf, const u16* __restrict__ Kf,
    const u16* __restrict__ Vf, float* __restrict__ part, float* __restrict__ ml)
{
    __shared__ u16 P[32 * 40];
    const int bid = blockIdx.x;
    const int s   = bid / (NHEAD * QT);
    const int rem = bid % (NHEAD * QT);
    const int h   = rem / QT;
    const int qt  = rem % QT;
    const int lane = threadIdx.x;
    const int kq = lane & 31;
    const int hi = lane >> 5;
    const int q0 = qt * 32;
    const int lxy = kq * 16 + hi * 8;       // chunk offset within fragment plane
    const u16* Kh = Kf + ((size_t)h * NT * 4 << 9);
    const u16* Vh = Vf + ((size_t)h * NT * 4 << 9);

    short8 qf[4];
#pragma unroll
    for (int d = 0; d < 4; d++)
        qf[d] = *(const short8*)(Qf + (((size_t)(h * NT + qt) * 4 + d) << 9) + lxy);

    f32x16 o0 = ZERO16, o1 = ZERO16;
    float mr = -3.0e38f, lr = 0.f;

    short8 kf[4];
#pragma unroll
    for (int d = 0; d < 4; d++)
        kf[d] = *(const short8*)(Kh + (((size_t)(s * TILES_PER_SPLIT) * 4 + d) << 9) + lxy);

    for (int i = 0; i < TILES_PER_SPLIT; i++) {
        const int tile = s * TILES_PER_SPLIT + i;
        const int k0 = tile * 32;
        short8 vv[4];
#pragma unroll
        for (int fd = 0; fd < 4; fd++)
            vv[fd] = *(const short8*)(Vh + (((size_t)tile * 4 + fd) << 9) + lxy);

        f32x16 st = ZERO16;
#pragma unroll
        for (int d = 0; d < 4; d++)
            st = __builtin_amdgcn_mfma_f32_32x32x16_bf16(kf[d], qf[d], st, 0, 0, 0);

        if (i < TILES_PER_SPLIT - 1) {   // prefetch next K tile
#pragma unroll
            for (int d = 0; d < 4; d++)
                kf[d] = *(const short8*)(Kh + (((size_t)(tile + 1) * 4 + d) << 9) + lxy);
        }

        if (k0 + 32 > M_VALID) {         // mask pad keys
#pragma unroll
            for (int r = 0; r < 16; r++) {
                int key = k0 + (r & 3) + 8 * (r >> 2) + 4 * hi;
                if (key >= M_VALID) st[r] = -3.0e38f;
            }
        }
        attn_tile(st, mr, lr, o0, o1, P, vv, kq, hi);
    }

    // write fp32 partials
#pragma unroll
    for (int r = 0; r < 16; r++) {
        int rl = (r & 3) + 8 * (r >> 2) + 4 * hi;
        int qrow = q0 + rl;
        if (qrow < M_VALID) {
            float* pp = part + ((size_t)s * M_PAD + qrow) * DH + h * 64;
            pp[kq] = o0[r];
            pp[kq + 32] = o1[r];
        }
    }
    if (hi == 0 && q0 + kq < M_VALID) {
        float* mlp = ml + (((size_t)s * NHEAD + h) * M_PAD + q0 + kq) * 2;
        mlp[0] = mr; mlp[1] = lr;
    }
}

// ---------------- merge KV-split partials -> bf16 obf (permuted rows) ----------------
__global__ __launch_bounds__(256) void attn_merge_kernel(
    const float* __restrict__ part, const float* __restrict__ ml, u16* __restrict__ obf)
{
    const int q = blockIdx.x;           // 0..M_VALID-1
    const int t = threadIdx.x;
    const int h = t >> 4, i = t & 15;   // head, 4-dim group
    float m[NSPLIT], l[NSPLIT];
#pragma unroll
    for (int s = 0; s < NSPLIT; s++) {
        const float* mlp = ml + (((size_t)s * NHEAD + h) * M_PAD + q) * 2;
        m[s] = mlp[0]; l[s] = mlp[1];
    }
    float M = fmaxf(fmaxf(m[0], m[1]), m[2]);
    float c[NSPLIT], L = 0.f;
#pragma unroll
    for (int s = 0; s < NSPLIT; s++) { c[s] = __expf(m[s] - M); L += c[s] * l[s]; }
    float inv = 1.0f / L;
    float4 acc = {0.f, 0.f, 0.f, 0.f};
#pragma unroll
    for (int s = 0; s < NSPLIT; s++) {
        float4 v = *(const float4*)(part + ((size_t)s * M_PAD + q) * DH + h * 64 + i * 4);
        acc.x += c[s] * v.x; acc.y += c[s] * v.y; acc.z += c[s] * v.z; acc.w += c[s] * v.w;
    }
    int mrow = (q % 3) * 880 + q / 3;   // (S,T) -> (T,S) permute
    short4v w;
    w[0] = (short)f2b(acc.x * inv); w[1] = (short)f2b(acc.y * inv);
    w[2] = (short)f2b(acc.z * inv); w[3] = (short)f2b(acc.w * inv);
    *(short4v*)(obf + (size_t)mrow * DH + h * 64 + i * 4) = w;
}

// ---------------- launch ----------------
extern "C" void kernel_launch(void* const* d_in, const int* in_sizes, int n_in,
                              void* d_out, int out_size, void* d_ws, size_t ws_size,
                              hipStream_t stream)
{
    const float* x      = (const float*)d_in[0];
    const float* cond   = (const float*)d_in[1];
    const float* w1     = (const float*)d_in[2];
    const float* b1     = (const float*)d_in[3];
    const float* w2     = (const float*)d_in[4];
    const float* b2     = (const float*)d_in[5];
    const float* ln_g   = (const float*)d_in[6];
    const float* ln_b   = (const float*)d_in[7];
    const float* wqkv   = (const float*)d_in[8];
    const float* bqkv   = (const float*)d_in[9];
    const float* qn_w   = (const float*)d_in[10];
    const float* kn_w   = (const float*)d_in[11];
    const float* wproj  = (const float*)d_in[12];
    const float* bproj  = (const float*)d_in[13];
    float* out = (float*)d_out;

    char* ws = (char*)d_ws;
    size_t off = 0;
    auto alloc = [&](size_t bytes) { size_t o = off; off += (bytes + 255) & ~(size_t)255; return o; };

    size_t off_fused  = alloc((size_t)M_PAD * K1P * 2);
    size_t off_w1t    = alloc((size_t)DH * K1P * 2);
    size_t off_w2t    = alloc((size_t)DH * DH * 2);
    size_t off_wqkvt  = alloc((size_t)3072 * DH * 2);
    size_t off_wprojt = alloc((size_t)CIMG * DH * 2);
    size_t off_h1     = alloc((size_t)M_PAD * DH * 2);   // ┐ reused by attn as fp32
    size_t off_h2     = alloc((size_t)M_PAD * DH * 2);   // │ partial buffer:
    size_t off_h2ln   = alloc((size_t)M_PAD * DH * 2);   // │ 3 * M_PAD*DH*4 bytes
    size_t off_qkv    = alloc((size_t)M_PAD * 3072 * 2); // ┘ = exactly these 4 regions
    size_t off_qf     = alloc((size_t)NHEAD * NT * 4 * 512 * 2);
    size_t off_kf     = alloc((size_t)NHEAD * NT * 4 * 512 * 2);
    size_t off_vf     = alloc((size_t)NHEAD * NT * 4 * 512 * 2);
    size_t off_obf    = alloc((size_t)M_PAD * DH * 2);
    (void)ws_size;

    u16* fused  = (u16*)(ws + off_fused);
    u16* w1t    = (u16*)(ws + off_w1t);
    u16* w2t    = (u16*)(ws + off_w2t);
    u16* wqkvt  = (u16*)(ws + off_wqkvt);
    u16* wprojt = (u16*)(ws + off_wprojt);
    u16* h1     = (u16*)(ws + off_h1);
    u16* h2     = (u16*)(ws + off_h2);
    u16* h2ln   = (u16*)(ws + off_h2ln);
    u16* qkvb   = (u16*)(ws + off_qkv);
    u16* Qf     = (u16*)(ws + off_qf);
    u16* Kf     = (u16*)(ws + off_kf);
    u16* Vf     = (u16*)(ws + off_vf);
    u16* obf    = (u16*)(ws + off_obf);
    float* part = (float*)(ws + off_h1);     // 3*M_PAD*DH fp32 over dead h1..qkv
    float* mlbf = (float*)(ws + off_fused);  // over dead fused

    // zero fused pad rows (feed gemm1)
    hipMemsetAsync(ws + off_fused + (size_t)M_VALID * K1P * 2, 0, (size_t)(M_PAD - M_VALID) * K1P * 2, stream);

    build_fused_kernel<<<M_VALID, 256, 0, stream>>>(x, cond, fused);
    transpose_bf16_kernel<<<dim3(DH / 32, K1P / 32), 256, 0, stream>>>(w1, w1t, K1, DH, K1P);
    transpose_bf16_kernel<<<dim3(DH / 32, DH / 32), 256, 0, stream>>>(w2, w2t, DH, DH, DH);
    transpose_bf16_kernel<<<dim3(3072 / 32, DH / 32), 256, 0, stream>>>(wqkv, wqkvt, DH, 3072, DH);
    transpose_bf16_kernel<<<dim3(CIMG / 32, DH / 32), 256, 0, stream>>>(wproj, wprojt, DH, CIMG, DH);

    gemm_kernel<0, 64><<<dim3(DH / 64, M_PAD / 128), 256, 0, stream>>>(fused, w1t, b1, nullptr, h1, nullptr, DH, K1P, M_PAD);
    gemm_kernel<1, 64><<<dim3(DH / 64, M_PAD / 128), 256, 0, stream>>>(h1, w2t, b2, nullptr, h2, nullptr, DH, DH, M_PAD);
    ln_kernel<<<M_PAD, 256, 0, stream>>>(h2, ln_g, ln_b, h2ln);
    gemm_kernel<1, 128><<<dim3(3072 / 128, M_PAD / 128), 256, 0, stream>>>(h2ln, wqkvt, bqkv, nullptr, qkvb, nullptr, 3072, DH, M_PAD);
    fragmentize_kernel<<<dim3(NT, 2), 256, 0, stream>>>(qkvb, qn_w, kn_w, Qf, Kf, Vf);
    attn_kernel<<<dim3(NSPLIT * NHEAD * QT), 64, 0, stream>>>(Qf, Kf, Vf, part, mlbf);
    attn_merge_kernel<<<M_VALID, 256, 0, stream>>>(part, mlbf, obf);
    gemm_kernel<2, 128><<<dim3(CIMG / 128, M_PAD / 128), 256, 0, stream>>>(obf, wprojt, bproj, x, nullptr, out, CIMG, DH, M_VALID);
}

// Round 6
// 226.974 us; speedup vs baseline: 1.4960x; 1.1773x over previous
//
#include <hip/hip_runtime.h>
#include <hip/hip_bf16.h>

typedef __attribute__((ext_vector_type(8))) short short8;
typedef __attribute__((ext_vector_type(4))) short short4v;
typedef __attribute__((ext_vector_type(4))) float f32x4;
typedef __attribute__((ext_vector_type(16))) float f32x16;
typedef unsigned short u16;

#define ZERO16 (f32x16){0,0,0,0,0,0,0,0,0,0,0,0,0,0,0,0}

__device__ __forceinline__ float b2f(u16 h) {
    unsigned u = ((unsigned)h) << 16;
    float f; __builtin_memcpy(&f, &u, 4); return f;
}
__device__ __forceinline__ u16 f2b(float f) {   // RTNE via HIP intrinsic
    __hip_bfloat16 h = __float2bfloat16(f);
    u16 r; __builtin_memcpy(&r, &h, 2); return r;
}
__device__ __forceinline__ void gload16(const void* g, void* l) {
    __builtin_amdgcn_global_load_lds(
        (const __attribute__((address_space(1))) unsigned*)g,
        (__attribute__((address_space(3))) unsigned*)l, 16, 0, 0);
}

// ---------------- problem constants ----------------
#define M_VALID 2640          // B*S*T tokens
#define M_PAD   2688          // 21 * 128
#define K1      3096          // 3072 + 24
#define K1P     3136          // padded to multiple of 64
#define DH      1024
#define CIMG    3072
#define NHEAD   16
#define NT      84            // 32-token tiles (2688 tokens)
#define QT      83            // q-tiles used (covers 2640)
#define NSPLIT  3
#define TILES_PER_SPLIT 28    // 3*28 = 84 tiles

// ---------------- build fused input (bf16) ----------------
__global__ __launch_bounds__(256) void build_fused_kernel(
    const float* __restrict__ x, const float* __restrict__ cond,
    u16* __restrict__ fused)
{
    int n = blockIdx.x;
    int tid = threadIdx.x;
    const float* xr = x + (size_t)n * CIMG;
    u16* fr = fused + (size_t)n * K1P;
    for (int c = tid * 4; c < CIMG; c += 1024) {
        float4 v = *(const float4*)(xr + c);
        short4v w;
        w[0] = (short)f2b(v.x); w[1] = (short)f2b(v.y);
        w[2] = (short)f2b(v.z); w[3] = (short)f2b(v.w);
        *(short4v*)(fr + c) = w;
    }
    if (tid < 16) {                      // pad cols 3072..3136 (24 real + zeros)
        int t = n % 3;
        short4v w;
        for (int jj = 0; jj < 4; jj++) {
            int j = tid * 4 + jj;
            float val = 0.f;
            if (j < 24) {
                int f = t * 4 + (j >> 1);          // row in mouse_padded (20 rows, first 8 zero)
                if (f >= 8) val = cond[(f - 8) * 2 + (j & 1)];
            }
            w[jj] = (short)f2b(val);
        }
        *(short4v*)(fr + CIMG + tid * 4) = w;
    }
}

// ---------------- transpose fp32 [K][N] -> bf16 [N][ldt] ----------------
__global__ __launch_bounds__(256) void transpose_bf16_kernel(
    const float* __restrict__ W, u16* __restrict__ Wt, int K, int N, int ldt)
{
    __shared__ float t[32][33];
    int n0 = blockIdx.x * 32, k0 = blockIdx.y * 32;
    int x = threadIdx.x & 31, y0 = threadIdx.x >> 5;   // 32x8
    for (int yy = y0; yy < 32; yy += 8) {
        int k = k0 + yy, n = n0 + x;
        t[yy][x] = (k < K && n < N) ? W[(size_t)k * N + n] : 0.f;
    }
    __syncthreads();
    for (int yy = y0; yy < 32; yy += 8) {
        int n = n0 + yy, k = k0 + x;
        if (n < N && k < ldt) Wt[(size_t)n * ldt + k] = f2b(t[x][yy]);
    }
}

// ---------------- GEMM: C[M][N] = A[M][K] @ Bt[N][K]^T  (bf16 in, f32 acc) ----------------
// 2-phase pipeline: stage(t+1) -> compute(t) -> ONE barrier. BK=64, dbuf LDS,
// XOR-16B swizzle via pre-swizzled global source (linear gload_lds dest).
template<int EPI, int BN>
__global__ __launch_bounds__(256) void gemm_kernel(
    const u16* __restrict__ A, const u16* __restrict__ Bt,
    const float* __restrict__ bias, const float* __restrict__ resid,
    u16* __restrict__ Cb, float* __restrict__ Cf,
    int N, int K, int Mvalid)
{
    constexpr int NJ = BN / 32;
    __shared__ u16 As[2][128 * 64];
    __shared__ u16 Bs[2][BN * 64];
    const int tid = threadIdx.x;
    const int lane = tid & 63, wid = tid >> 6;
    const int l15 = lane & 15, l4 = lane >> 4;
    const int m0 = blockIdx.y * 128, n0 = blockIdx.x * BN;
    const int wr = (wid >> 1) * 64, wc = (wid & 1) * (BN / 2);

    // staging geometry: chunk = 1KB = 8 rows x 64 u16; lane l covers row c*8+(l>>3),
    // physical 16B slot (l&7); source column pre-swizzled so that readers can XOR.
    const int srow = lane >> 3;
    const int scol = ((lane & 7) ^ (lane >> 3)) << 3;   // u16 offset within BK=64

    f32x4 acc[4][NJ];
#pragma unroll
    for (int i = 0; i < 4; i++)
#pragma unroll
        for (int j = 0; j < NJ; j++) acc[i][j] = (f32x4){0.f, 0.f, 0.f, 0.f};

    const int nt = K >> 6;

    auto stage = [&](int buf, int k0) {
#pragma unroll
        for (int i = 0; i < 4; i++) {
            int c = wid * 4 + i;                     // A chunks 0..15
            gload16(A + (size_t)(m0 + c * 8 + srow) * K + k0 + scol,
                    (char*)&As[buf][0] + c * 1024 + lane * 16);
        }
#pragma unroll
        for (int i = 0; i < NJ; i++) {
            int c = wid * NJ + i;                    // B chunks 0..BN/8-1
            gload16(Bt + (size_t)(n0 + c * 8 + srow) * K + k0 + scol,
                    (char*)&Bs[buf][0] + c * 1024 + lane * 16);
        }
    };

    stage(0, 0);
    __syncthreads();
    int cur = 0;
    for (int t = 0; t < nt; t++) {
        if (t + 1 < nt) stage(cur ^ 1, (t + 1) * 64);
#pragma unroll
        for (int ki = 0; ki < 2; ki++) {
            short8 af[4], bfr[NJ];
#pragma unroll
            for (int i = 0; i < 4; i++) {
                int row = wr + i * 16 + l15;
                af[i] = *(const short8*)((const char*)&As[cur][0]
                        + row * 128 + (((ki * 4 + l4) ^ (l15 & 7)) << 4));
            }
#pragma unroll
            for (int j = 0; j < NJ; j++) {
                int row = wc + j * 16 + l15;
                bfr[j] = *(const short8*)((const char*)&Bs[cur][0]
                        + row * 128 + (((ki * 4 + l4) ^ (l15 & 7)) << 4));
            }
#pragma unroll
            for (int i = 0; i < 4; i++)
#pragma unroll
                for (int j = 0; j < NJ; j++)
                    acc[i][j] = __builtin_amdgcn_mfma_f32_16x16x32_bf16(af[i], bfr[j], acc[i][j], 0, 0, 0);
        }
        __syncthreads();
        cur ^= 1;
    }

#pragma unroll
    for (int i = 0; i < 4; i++) {
#pragma unroll
        for (int j = 0; j < NJ; j++) {
#pragma unroll
            for (int r = 0; r < 4; r++) {
                int row = m0 + wr + i * 16 + l4 * 4 + r;
                int col = n0 + wc + j * 16 + l15;
                float v = acc[i][j][r] + bias[col];
                if (EPI == 0) {
                    float t = v + 0.044715f * v * v * v;
                    float g = 0.5f * v * (1.0f + tanhf(0.7978845608028654f * t));
                    Cb[(size_t)row * N + col] = f2b(g);
                } else if (EPI == 1) {
                    Cb[(size_t)row * N + col] = f2b(v);
                } else {
                    if (row < Mvalid)
                        Cf[(size_t)row * N + col] = v + resid[(size_t)row * N + col];
                }
            }
        }
    }
}

// ---------------- LayerNorm over 1024 (bf16 -> bf16) ----------------
__global__ __launch_bounds__(256) void ln_kernel(
    const u16* __restrict__ h2, const float* __restrict__ g,
    const float* __restrict__ b, u16* __restrict__ out)
{
    int row = blockIdx.x;
    int tid = threadIdx.x;
    const u16* p = h2 + (size_t)row * DH;
    float v[4];
#pragma unroll
    for (int i = 0; i < 4; i++) v[i] = b2f(p[tid * 4 + i]);
    float s1 = v[0] + v[1] + v[2] + v[3];
    float s2 = v[0]*v[0] + v[1]*v[1] + v[2]*v[2] + v[3]*v[3];
    for (int m = 1; m < 64; m <<= 1) { s1 += __shfl_xor(s1, m); s2 += __shfl_xor(s2, m); }
    __shared__ float a1[4], a2[4];
    int w = tid >> 6;
    if ((tid & 63) == 0) { a1[w] = s1; a2[w] = s2; }
    __syncthreads();
    s1 = a1[0] + a1[1] + a1[2] + a1[3];
    s2 = a2[0] + a2[1] + a2[2] + a2[3];
    float mean = s1 * (1.0f / 1024.0f);
    float var = s2 * (1.0f / 1024.0f) - mean * mean;
    float rs = rsqrtf(var + 1e-5f);
    u16* q = out + (size_t)row * DH;
#pragma unroll
    for (int i = 0; i < 4; i++) {
        int c = tid * 4 + i;
        q[c] = f2b((v[i] - mean) * rs * g[c] + b[c]);
    }
}

// ---------------- fragmentize: RMSNorm(q,k) + MFMA-fragment layout for Q,K,V ----------------
__global__ __launch_bounds__(256) void fragmentize_kernel(
    const u16* __restrict__ qkv, const float* __restrict__ qw, const float* __restrict__ kw,
    u16* __restrict__ Qf, u16* __restrict__ Kf, u16* __restrict__ Vf)
{
    __shared__ u16 Vlds[8 * 32 * 80];    // [hh][token][dim], row stride 80
    const int kt = blockIdx.x;           // 0..NT-1
    const int hg = blockIdx.y;           // 0..1 (8 heads each)
    const int tid = threadIdx.x;
    const int t32 = tid >> 3, c8 = tid & 7;
    const int n = kt * 32 + t32;
    const u16* row = qkv + (size_t)n * 3072;

    // stage V into LDS
#pragma unroll
    for (int hh = 0; hh < 8; hh++) {
        short8 v = *(const short8*)(row + 2048 + (hg * 8 + hh) * 64 + c8 * 8);
        *(short8*)(&Vlds[(hh * 32 + t32) * 80 + c8 * 8]) = v;
    }

    // q/k sum of squares per head (8 threads per token, xor-reduce over c8)
    float sq[8], sk[8];
#pragma unroll
    for (int hh = 0; hh < 8; hh++) {
        int h = hg * 8 + hh;
        short8 qv = *(const short8*)(row + h * 64 + c8 * 8);
        short8 kv = *(const short8*)(row + 1024 + h * 64 + c8 * 8);
        float aq = 0.f, ak = 0.f;
#pragma unroll
        for (int e = 0; e < 8; e++) {
            float fq = b2f((u16)qv[e]); aq += fq * fq;
            float fk = b2f((u16)kv[e]); ak += fk * fk;
        }
        sq[hh] = aq; sk[hh] = ak;
    }
#pragma unroll
    for (int m = 1; m < 8; m <<= 1) {
#pragma unroll
        for (int hh = 0; hh < 8; hh++) {
            sq[hh] += __shfl_xor(sq[hh], m);
            sk[hh] += __shfl_xor(sk[hh], m);
        }
    }

    float qwv[8], kwv[8];
#pragma unroll
    for (int e = 0; e < 8; e++) { qwv[e] = qw[c8 * 8 + e]; kwv[e] = kw[c8 * 8 + e]; }

    // normalize + write Q/K fragments (fold 1/sqrt(64) into q)
#pragma unroll
    for (int hh = 0; hh < 8; hh++) {
        int h = hg * 8 + hh;
        float rq = rsqrtf(sq[hh] * (1.0f / 64.0f) + 1e-6f) * 0.125f;
        float rk = rsqrtf(sk[hh] * (1.0f / 64.0f) + 1e-6f);
        short8 qv = *(const short8*)(row + h * 64 + c8 * 8);
        short8 kv = *(const short8*)(row + 1024 + h * 64 + c8 * 8);
        short8 qo, ko;
#pragma unroll
        for (int e = 0; e < 8; e++) {
            qo[e] = (short)f2b(b2f((u16)qv[e]) * rq * qwv[e]);
            ko[e] = (short)f2b(b2f((u16)kv[e]) * rk * kwv[e]);
        }
        size_t base = (((size_t)(h * NT + kt) * 4 + (c8 >> 1)) << 9) + t32 * 16 + (c8 & 1) * 8;
        *(short8*)(Qf + base) = qo;
        *(short8*)(Kf + base) = ko;
    }

    __syncthreads();

    // transposed V fragments
    const int fd = tid >> 6;             // 0..3
    const int lkq = (tid & 63) >> 1, lhi = tid & 1;
#pragma unroll
    for (int hh = 0; hh < 8; hh++) {
        int h = hg * 8 + hh;
        short8 o;
#pragma unroll
        for (int e = 0; e < 8; e++)
            o[e] = (short)Vlds[(hh * 32 + (fd & 1) * 16 + lhi * 8 + e) * 80 + (fd >> 1) * 32 + lkq];
        *(short8*)(Vf + (((size_t)(h * NT + kt) * 4 + fd) << 9) + lkq * 16 + lhi * 8) = o;
    }
}

// ---------------- attention tile: softmax + PV ----------------
__device__ __forceinline__ void attn_tile(
    f32x16& st, float& mr, float& lr, f32x16& o0, f32x16& o1,
    u16* Pbuf, const short8* vv, int kq, int hi)
{
    float tmax = st[0];
#pragma unroll
    for (int r = 1; r < 16; r++) tmax = fmaxf(tmax, st[r]);
    tmax = fmaxf(tmax, __shfl_xor(tmax, 32));
    if (__any(tmax - mr > 8.0f)) {       // defer-max (T13)
        float mn = fmaxf(mr, tmax);
        float corr = __expf(mr - mn);
        mr = mn; lr *= corr;
#pragma unroll
        for (int r = 0; r < 16; r++) {   // per-O-row factor: O rows are query rl, not kq
            float cr = __shfl(corr, (r & 3) + 8 * (r >> 2) + 4 * hi);
            o0[r] *= cr; o1[r] *= cr;
        }
    }
    float sum = 0.f;
    float p[16];
#pragma unroll
    for (int r = 0; r < 16; r++) { p[r] = __expf(st[r] - mr); sum += p[r]; }
    lr += sum + __shfl_xor(sum, 32);
#pragma unroll
    for (int g = 0; g < 4; g++) {
        short4v w;
#pragma unroll
        for (int e = 0; e < 4; e++) w[e] = (short)f2b(p[g * 4 + e]);
        *(short4v*)((char*)Pbuf + kq * 80 + g * 16 + hi * 8) = w;
    }
    short8 pa0 = *(const short8*)((const char*)Pbuf + kq * 80 + hi * 16);
    short8 pa1 = *(const short8*)((const char*)Pbuf + kq * 80 + 32 + hi * 16);
    o0 = __builtin_amdgcn_mfma_f32_32x32x16_bf16(pa0, vv[0], o0, 0, 0, 0);
    o0 = __builtin_amdgcn_mfma_f32_32x32x16_bf16(pa1, vv[1], o0, 0, 0, 0);
    o1 = __builtin_amdgcn_mfma_f32_32x32x16_bf16(pa0, vv[2], o1, 0, 0, 0);
    o1 = __builtin_amdgcn_mfma_f32_32x32x16_bf16(pa1, vv[3], o1, 0, 0, 0);
}

// ---------------- flash attention, KV-split, fragment inputs ----------------
__global__ __launch_bounds__(64, 4) void attn_kernel(
    const u16* __restrict__ Qf, const u16* __restrict__ Kf,
    const u16* __restrict__ Vf, float* __restrict__ part, float* __restrict__ ml)
{
    __shared__ u16 P[32 * 40];
    const int bid = blockIdx.x;
    const int s   = bid / (NHEAD * QT);
    const int rem = bid % (NHEAD * QT);
    const int h   = rem / QT;
    const int qt  = rem % QT;
    const int lane = threadIdx.x;
    const int kq = lane & 31;
    const int hi = lane >> 5;
    const int q0 = qt * 32;
    const int lxy = kq * 16 + hi * 8;       // chunk offset within fragment plane
    const u16* Kh = Kf + ((size_t)h * NT * 4 << 9);
    const u16* Vh = Vf + ((size_t)h * NT * 4 << 9);

    short8 qf[4];
#pragma unroll
    for (int d = 0; d < 4; d++)
        qf[d] = *(const short8*)(Qf + (((size_t)(h * NT + qt) * 4 + d) << 9) + lxy);

    f32x16 o0 = ZERO16, o1 = ZERO16;
    float mr = -3.0e38f, lr = 0.f;

    short8 kf[4];
#pragma unroll
    for (int d = 0; d < 4; d++)
        kf[d] = *(const short8*)(Kh + (((size_t)(s * TILES_PER_SPLIT) * 4 + d) << 9) + lxy);

    for (int i = 0; i < TILES_PER_SPLIT; i++) {
        const int tile = s * TILES_PER_SPLIT + i;
        const int k0 = tile * 32;
        short8 vv[4];
#pragma unroll
        for (int fd = 0; fd < 4; fd++)
            vv[fd] = *(const short8*)(Vh + (((size_t)tile * 4 + fd) << 9) + lxy);

        f32x16 st = ZERO16;
#pragma unroll
        for (int d = 0; d < 4; d++)
            st = __builtin_amdgcn_mfma_f32_32x32x16_bf16(kf[d], qf[d], st, 0, 0, 0);

        if (i < TILES_PER_SPLIT - 1) {   // prefetch next K tile
#pragma unroll
            for (int d = 0; d < 4; d++)
                kf[d] = *(const short8*)(Kh + (((size_t)(tile + 1) * 4 + d) << 9) + lxy);
        }

        if (k0 + 32 > M_VALID) {         // mask pad keys
#pragma unroll
            for (int r = 0; r < 16; r++) {
                int key = k0 + (r & 3) + 8 * (r >> 2) + 4 * hi;
                if (key >= M_VALID) st[r] = -3.0e38f;
            }
        }
        attn_tile(st, mr, lr, o0, o1, P, vv, kq, hi);
    }

    // write fp32 partials
#pragma unroll
    for (int r = 0; r < 16; r++) {
        int rl = (r & 3) + 8 * (r >> 2) + 4 * hi;
        int qrow = q0 + rl;
        if (qrow < M_VALID) {
            float* pp = part + ((size_t)s * M_PAD + qrow) * DH + h * 64;
            pp[kq] = o0[r];
            pp[kq + 32] = o1[r];
        }
    }
    if (hi == 0 && q0 + kq < M_VALID) {
        float* mlp = ml + (((size_t)s * NHEAD + h) * M_PAD + q0 + kq) * 2;
        mlp[0] = mr; mlp[1] = lr;
    }
}

// ---------------- merge KV-split partials -> bf16 obf (permuted rows) ----------------
__global__ __launch_bounds__(256) void attn_merge_kernel(
    const float* __restrict__ part, const float* __restrict__ ml, u16* __restrict__ obf)
{
    const int q = blockIdx.x;           // 0..M_VALID-1
    const int t = threadIdx.x;
    const int h = t >> 4, i = t & 15;   // head, 4-dim group
    float m[NSPLIT], l[NSPLIT];
#pragma unroll
    for (int s = 0; s < NSPLIT; s++) {
        const float* mlp = ml + (((size_t)s * NHEAD + h) * M_PAD + q) * 2;
        m[s] = mlp[0]; l[s] = mlp[1];
    }
    float M = fmaxf(fmaxf(m[0], m[1]), m[2]);
    float c[NSPLIT], L = 0.f;
#pragma unroll
    for (int s = 0; s < NSPLIT; s++) { c[s] = __expf(m[s] - M); L += c[s] * l[s]; }
    float inv = 1.0f / L;
    float4 acc = {0.f, 0.f, 0.f, 0.f};
#pragma unroll
    for (int s = 0; s < NSPLIT; s++) {
        float4 v = *(const float4*)(part + ((size_t)s * M_PAD + q) * DH + h * 64 + i * 4);
        acc.x += c[s] * v.x; acc.y += c[s] * v.y; acc.z += c[s] * v.z; acc.w += c[s] * v.w;
    }
    int mrow = (q % 3) * 880 + q / 3;   // (S,T) -> (T,S) permute
    short4v w;
    w[0] = (short)f2b(acc.x * inv); w[1] = (short)f2b(acc.y * inv);
    w[2] = (short)f2b(acc.z * inv); w[3] = (short)f2b(acc.w * inv);
    *(short4v*)(obf + (size_t)mrow * DH + h * 64 + i * 4) = w;
}

// ---------------- launch ----------------
extern "C" void kernel_launch(void* const* d_in, const int* in_sizes, int n_in,
                              void* d_out, int out_size, void* d_ws, size_t ws_size,
                              hipStream_t stream)
{
    const float* x      = (const float*)d_in[0];
    const float* cond   = (const float*)d_in[1];
    const float* w1     = (const float*)d_in[2];
    const float* b1     = (const float*)d_in[3];
    const float* w2     = (const float*)d_in[4];
    const float* b2     = (const float*)d_in[5];
    const float* ln_g   = (const float*)d_in[6];
    const float* ln_b   = (const float*)d_in[7];
    const float* wqkv   = (const float*)d_in[8];
    const float* bqkv   = (const float*)d_in[9];
    const float* qn_w   = (const float*)d_in[10];
    const float* kn_w   = (const float*)d_in[11];
    const float* wproj  = (const float*)d_in[12];
    const float* bproj  = (const float*)d_in[13];
    float* out = (float*)d_out;

    char* ws = (char*)d_ws;
    size_t off = 0;
    auto alloc = [&](size_t bytes) { size_t o = off; off += (bytes + 255) & ~(size_t)255; return o; };

    size_t off_fused  = alloc((size_t)M_PAD * K1P * 2);
    size_t off_w1t    = alloc((size_t)DH * K1P * 2);
    size_t off_w2t    = alloc((size_t)DH * DH * 2);
    size_t off_wqkvt  = alloc((size_t)3072 * DH * 2);
    size_t off_wprojt = alloc((size_t)CIMG * DH * 2);
    size_t off_h1     = alloc((size_t)M_PAD * DH * 2);   // ┐ reused by attn as fp32
    size_t off_h2     = alloc((size_t)M_PAD * DH * 2);   // │ partial buffer:
    size_t off_h2ln   = alloc((size_t)M_PAD * DH * 2);   // │ 3 * M_PAD*DH*4 bytes
    size_t off_qkv    = alloc((size_t)M_PAD * 3072 * 2); // ┘ = exactly these 4 regions
    size_t off_qf     = alloc((size_t)NHEAD * NT * 4 * 512 * 2);
    size_t off_kf     = alloc((size_t)NHEAD * NT * 4 * 512 * 2);
    size_t off_vf     = alloc((size_t)NHEAD * NT * 4 * 512 * 2);
    size_t off_obf    = alloc((size_t)M_PAD * DH * 2);
    (void)ws_size;

    u16* fused  = (u16*)(ws + off_fused);
    u16* w1t    = (u16*)(ws + off_w1t);
    u16* w2t    = (u16*)(ws + off_w2t);
    u16* wqkvt  = (u16*)(ws + off_wqkvt);
    u16* wprojt = (u16*)(ws + off_wprojt);
    u16* h1     = (u16*)(ws + off_h1);
    u16* h2     = (u16*)(ws + off_h2);
    u16* h2ln   = (u16*)(ws + off_h2ln);
    u16* qkvb   = (u16*)(ws + off_qkv);
    u16* Qf     = (u16*)(ws + off_qf);
    u16* Kf     = (u16*)(ws + off_kf);
    u16* Vf     = (u16*)(ws + off_vf);
    u16* obf    = (u16*)(ws + off_obf);
    float* part = (float*)(ws + off_h1);     // 3*M_PAD*DH fp32 over dead h1..qkv
    float* mlbf = (float*)(ws + off_fused);  // over dead fused

    // zero fused pad rows (feed gemm1)
    hipMemsetAsync(ws + off_fused + (size_t)M_VALID * K1P * 2, 0, (size_t)(M_PAD - M_VALID) * K1P * 2, stream);

    build_fused_kernel<<<M_VALID, 256, 0, stream>>>(x, cond, fused);
    transpose_bf16_kernel<<<dim3(DH / 32, K1P / 32), 256, 0, stream>>>(w1, w1t, K1, DH, K1P);
    transpose_bf16_kernel<<<dim3(DH / 32, DH / 32), 256, 0, stream>>>(w2, w2t, DH, DH, DH);
    transpose_bf16_kernel<<<dim3(3072 / 32, DH / 32), 256, 0, stream>>>(wqkv, wqkvt, DH, 3072, DH);
    transpose_bf16_kernel<<<dim3(CIMG / 32, DH / 32), 256, 0, stream>>>(wproj, wprojt, DH, CIMG, DH);

    gemm_kernel<0, 64><<<dim3(DH / 64, M_PAD / 128), 256, 0, stream>>>(fused, w1t, b1, nullptr, h1, nullptr, DH, K1P, M_PAD);
    gemm_kernel<1, 64><<<dim3(DH / 64, M_PAD / 128), 256, 0, stream>>>(h1, w2t, b2, nullptr, h2, nullptr, DH, DH, M_PAD);
    ln_kernel<<<M_PAD, 256, 0, stream>>>(h2, ln_g, ln_b, h2ln);
    gemm_kernel<1, 128><<<dim3(3072 / 128, M_PAD / 128), 256, 0, stream>>>(h2ln, wqkvt, bqkv, nullptr, qkvb, nullptr, 3072, DH, M_PAD);
    fragmentize_kernel<<<dim3(NT, 2), 256, 0, stream>>>(qkvb, qn_w, kn_w, Qf, Kf, Vf);
    attn_kernel<<<dim3(NSPLIT * NHEAD * QT), 64, 0, stream>>>(Qf, Kf, Vf, part, mlbf);
    attn_merge_kernel<<<M_VALID, 256, 0, stream>>>(part, mlbf, obf);
    gemm_kernel<2, 128><<<dim3(CIMG / 128, M_PAD / 128), 256, 0, stream>>>(obf, wprojt, bproj, x, nullptr, out, CIMG, DH, M_VALID);
}